// Round 2
// baseline (533.597 us; speedup 1.0000x reference)
//
#include <hip/hip_runtime.h>

#define NUM_C 512
#define HW    32768     // 128*256
#define K     19
#define NT    256
#define SPLIT 4                 // chunks per (b,c) plane
#define CHUNK (HW / SPLIT)      // 8192 elements per block
#define CP    (NUM_C + 4)       // padded LDS row stride in finalize

// ---------------------------------------------------------------------------
// K1: per-(b,c,chunk) segment sums. grid = 4096 blocks x 256 threads
// (8 blocks/CU -> full 32-wave occupancy; was 1024 blocks = 50% cap).
// The 19-way compare/select (76 VALU lane-ops/elem, ~32 us chip-wide) is
// replaced by a true scatter: 2 LDS ds_add_f32 per element into per-wave
// histograms. 2 sub-replicas per wave (lane&1) halve same-address
// serialization on random labels.
//
// NS = partial slots stored per plane:
//   NS==SPLIT : disjoint global slots (deterministic)  -- needs 623 KB ws
//   NS==1     : global atomicAdd combine (compact)     -- needs 156 KB ws
// ---------------------------------------------------------------------------
template <int NS>
__global__ __launch_bounds__(NT) void seg_sum_kernel(
    const float* __restrict__ S, const float* __restrict__ T,
    const int* __restrict__ lbl,
    float* __restrict__ pS, float* __restrict__ pT,
    int* __restrict__ pC,
    float* __restrict__ out)
{
    const int tid   = threadIdx.x;
    const int bid   = blockIdx.x;
    const int plane = bid >> 2;              // SPLIT == 4
    const int chunk = bid & (SPLIT - 1);
    const int b     = plane >> 9;
    const int c     = plane & 511;

    if (bid == 0 && tid == 0) out[0] = 0.f;  // zero-init for K2's atomicAdd

    // per-wave, 2-replica histograms: [wave][sub][20] (pad 19->20)
    __shared__ float hS[4][2][20];
    __shared__ float hT[4][2][20];
    for (int i = tid; i < 4 * 2 * 20; i += NT) {
        (&hS[0][0][0])[i] = 0.f;
        (&hT[0][0][0])[i] = 0.f;
    }
    __syncthreads();

    const int wv  = tid >> 6;
    const int sub = tid & 1;
    float* mS = &hS[wv][sub][0];
    float* mT = &hT[wv][sub][0];

    const float4* S4 = (const float4*)(S + (size_t)plane * HW + (size_t)chunk * CHUNK);
    const float4* T4 = (const float4*)(T + (size_t)plane * HW + (size_t)chunk * CHUNK);
    const int4*   L4 = (const int4*)(lbl + (size_t)b * HW + (size_t)chunk * CHUNK);

    for (int i = tid; i < CHUNK / 4; i += NT) {   // exactly 8 iterations
        float4 s = S4[i];
        float4 t = T4[i];
        int4   l = L4[i];
        atomicAdd(&mS[l.x], s.x); atomicAdd(&mT[l.x], t.x);
        atomicAdd(&mS[l.y], s.y); atomicAdd(&mT[l.y], t.y);
        atomicAdd(&mS[l.z], s.z); atomicAdd(&mT[l.z], t.z);
        atomicAdd(&mS[l.w], s.w); atomicAdd(&mT[l.w], t.w);
    }
    __syncthreads();

    if (tid < K) {
        float vs = 0.f, vt = 0.f;
#pragma unroll
        for (int w = 0; w < 4; ++w)
#pragma unroll
            for (int ss = 0; ss < 2; ++ss) {
                vs += hS[w][ss][tid];
                vt += hT[w][ss][tid];
            }
        if (NS == SPLIT) {
            pS[(size_t)bid * K + tid] = vs;
            pT[(size_t)bid * K + tid] = vt;
        } else {
            atomicAdd(&pS[(size_t)plane * K + tid], vs);
            atomicAdd(&pT[(size_t)plane * K + tid], vt);
        }
    }

    // label counts: only the 8 blocks with c==0 (block-uniform branch).
    if (c == 0) {
        int cnt[K];
#pragma unroll
        for (int k = 0; k < K; ++k) cnt[k] = 0;
        for (int i = tid; i < CHUNK / 4; i += NT) {
            int4 l = L4[i];
#pragma unroll
            for (int k = 0; k < K; ++k)
                cnt[k] += (l.x == k) + (l.y == k) + (l.z == k) + (l.w == k);
        }
        __shared__ int redc[4 * K];
        const int lane = tid & 63;
#pragma unroll
        for (int k = 0; k < K; ++k) {
            int v = cnt[k];
#pragma unroll
            for (int off = 32; off > 0; off >>= 1) v += __shfl_down(v, off);
            if (lane == 0) redc[wv * K + k] = v;
        }
        __syncthreads();
        if (tid < K)
            pC[(b * SPLIT + chunk) * K + tid] =
                redc[tid] + redc[K + tid] + redc[2 * K + tid] + redc[3 * K + tid];
    }
}

// ---------------------------------------------------------------------------
// K2: grid = 2 blocks (one per batch). Counts precomputed by K1's c==0
// blocks. Centers sum NS partial slots. Pairwise dots exploit symmetry:
// 190 upper-triangle tasks with fused S/T accumulation.
// ---------------------------------------------------------------------------
template <int NS>
__global__ __launch_bounds__(NT) void finalize_kernel(
    const float* __restrict__ pS, const float* __restrict__ pT,
    const int* __restrict__ pC, float* __restrict__ out)
{
    __shared__ float centS[K * CP];
    __shared__ float centT[K * CP];
    __shared__ float cntf[K];
    __shared__ float dS[K * K], dT[K * K];
    __shared__ float red[NT];
    const int tid = threadIdx.x;
    const int b   = blockIdx.x;

    if (tid < K) {
        int cv = 0;
#pragma unroll
        for (int ch = 0; ch < SPLIT; ++ch) cv += pC[(b * SPLIT + ch) * K + tid];
        cntf[tid] = (float)cv + 1e-6f;
    }
    __syncthreads();

    // centers: [k][c] layout, padded stride; sum NS partial slots
    for (int j = tid; j < NUM_C * K; j += NT) {
        int c = j / K, k = j - (j / K) * K;
        size_t base = ((size_t)(b * NUM_C + c) * NS) * K + k;
        float sS = 0.f, sT = 0.f;
#pragma unroll
        for (int ch = 0; ch < NS; ++ch) {
            sS += pS[base + (size_t)ch * K];
            sT += pT[base + (size_t)ch * K];
        }
        float cn = cntf[k];
        centS[k * CP + c] = sS / cn;
        centT[k * CP + c] = sT / cn;
    }
    __syncthreads();

    // upper-triangle pairwise dots: q in [0, K*(K+1)/2) = [0,190)
    for (int q = tid; q < K * (K + 1) / 2; q += NT) {
        int i = 0, r = q;
        while (r >= K - i) { r -= K - i; ++i; }
        int j = i + r;
        const float4* Si = (const float4*)(centS + i * CP);
        const float4* Sj = (const float4*)(centS + j * CP);
        const float4* Ti = (const float4*)(centT + i * CP);
        const float4* Tj = (const float4*)(centT + j * CP);
        float ds = 0.f, dt = 0.f;
        for (int c4 = 0; c4 < NUM_C / 4; ++c4) {
            float4 xs = Si[c4], ys = Sj[c4];
            ds = fmaf(xs.x, ys.x, ds); ds = fmaf(xs.y, ys.y, ds);
            ds = fmaf(xs.z, ys.z, ds); ds = fmaf(xs.w, ys.w, ds);
            float4 xt = Ti[c4], yt = Tj[c4];
            dt = fmaf(xt.x, yt.x, dt); dt = fmaf(xt.y, yt.y, dt);
            dt = fmaf(xt.z, yt.z, dt); dt = fmaf(xt.w, yt.w, dt);
        }
        dS[i * K + j] = ds; dS[j * K + i] = ds;
        dT[i * K + j] = dt; dT[j * K + i] = dt;
    }
    __syncthreads();

    // cosine-normalize via diagonal + squared diff
    float acc = 0.f;
    for (int p = tid; p < K * K; p += NT) {
        int i = p / K, j = p - (p / K) * K;
        float nsi = fmaxf(sqrtf(dS[i * K + i]), 1e-8f);
        float nsj = fmaxf(sqrtf(dS[j * K + j]), 1e-8f);
        float nti = fmaxf(sqrtf(dT[i * K + i]), 1e-8f);
        float ntj = fmaxf(sqrtf(dT[j * K + j]), 1e-8f);
        float d = dS[p] / (nsi * nsj) - dT[p] / (nti * ntj);
        acc = fmaf(d, d, acc);
    }
    red[tid] = acc;
    __syncthreads();
    for (int s = NT / 2; s > 0; s >>= 1) {
        if (tid < s) red[tid] += red[tid + s];
        __syncthreads();
    }
    if (tid == 0)
        atomicAdd(out, red[0] * (1.0f / (2.0f * K * K)));  // mean over [B,K,K]
}

extern "C" void kernel_launch(void* const* d_in, const int* in_sizes, int n_in,
                              void* d_out, int out_size, void* d_ws, size_t ws_size,
                              hipStream_t stream) {
    const float* S   = (const float*)d_in[0];   // preds_S  [2,512,128,256] fp32
    const float* T   = (const float*)d_in[1];   // preds_T  [2,512,128,256] fp32
    const int*   lbl = (const int*)d_in[2];     // target   [2,1,128,256] int32
    float* out = (float*)d_out;

    const size_t nPlane = (size_t)2 * NUM_C;            // 1024
    const size_t needBig =
        2 * nPlane * SPLIT * K * sizeof(float)          // pS + pT, SPLIT slots
        + (size_t)2 * SPLIT * K * sizeof(int);          // pC
    const size_t needSmall =
        2 * nPlane * K * sizeof(float)                  // pS + pT, 1 slot
        + (size_t)2 * SPLIT * K * sizeof(int);

    if (ws_size >= needBig) {
        // deterministic path: disjoint per-chunk partial slots
        float* pS = (float*)d_ws;
        float* pT = pS + nPlane * SPLIT * K;
        int*   pC = (int*)(pT + nPlane * SPLIT * K);
        seg_sum_kernel<SPLIT><<<2 * NUM_C * SPLIT, NT, 0, stream>>>(S, T, lbl, pS, pT, pC, out);
        finalize_kernel<SPLIT><<<2, NT, 0, stream>>>(pS, pT, pC, out);
    } else {
        // compact path (fits the round-0 footprint): atomic combine
        float* pS = (float*)d_ws;
        float* pT = pS + nPlane * K;
        int*   pC = (int*)(pT + nPlane * K);
        (void)needSmall;
        hipMemsetAsync(pS, 0, 2 * nPlane * K * sizeof(float), stream);
        seg_sum_kernel<1><<<2 * NUM_C * SPLIT, NT, 0, stream>>>(S, T, lbl, pS, pT, pC, out);
        finalize_kernel<1><<<2, NT, 0, stream>>>(pS, pT, pC, out);
    }
}

// Round 4
// 306.263 us; speedup vs baseline: 1.7423x; 1.7423x over previous
//
#include <hip/hip_runtime.h>

#define NUM_C 512
#define HW    32768     // 128*256
#define K     19
#define NT    256
#define SPLIT 2                 // chunks per (b,c) plane
#define CHUNK (HW / SPLIT)      // 16384 elements per block
#define CP    (NUM_C + 4)       // padded LDS row stride in finalize

// ---------------------------------------------------------------------------
// K1: per-(b,c,chunk) segment sums via branchless compare/select into
// REGISTER accumulators. (LDS-atomic scatter measured 4x slower in round 2:
// ~200 cyc per wave64 ds_add_f32; VALUBusy 1.2%, all pipes idle.)
// grid = 2048 blocks x 256 threads = 8192 waves = 100% occupancy at 36 VGPR
// (the 1024-block round-0 grid capped occupancy at 35% -> VALUBusy 43%).
// Per element: 19 x (v_cmp + v_cndmask + 2 v_fmac) = 76 VALU lane-ops.
// Chip VALU floor ~32 us; memory floor ~35-45 us (L3 absorbs ~half of the
// 268 MB) -> expect seg_sum ~55-65 us at full occupancy.
// NS = partial slots per plane: SPLIT (deterministic disjoint slots) or
// 1 (global-atomic combine, compact-workspace fallback).
// ---------------------------------------------------------------------------
template <int NS>
__global__ __launch_bounds__(NT) void seg_sum_kernel(
    const float* __restrict__ S, const float* __restrict__ T,
    const int* __restrict__ lbl,
    float* __restrict__ pS, float* __restrict__ pT,
    int* __restrict__ pC,
    float* __restrict__ out)
{
    const int tid   = threadIdx.x;
    const int bid   = blockIdx.x;
    const int plane = bid >> 1;              // SPLIT == 2
    const int chunk = bid & (SPLIT - 1);
    const int b     = plane >> 9;
    const int c     = plane & 511;

    if (bid == 0 && tid == 0) out[0] = 0.f;  // zero-init for K2's atomicAdd

    const float4* S4 = (const float4*)(S + (size_t)plane * HW + (size_t)chunk * CHUNK);
    const float4* T4 = (const float4*)(T + (size_t)plane * HW + (size_t)chunk * CHUNK);
    const int4*   L4 = (const int4*)(lbl + (size_t)b * HW + (size_t)chunk * CHUNK);

    float accS[K], accT[K];
#pragma unroll
    for (int k = 0; k < K; ++k) { accS[k] = 0.f; accT[k] = 0.f; }

    for (int i = tid; i < CHUNK / 4; i += NT) {   // exactly 16 iterations
        float4 s = S4[i];
        float4 t = T4[i];
        int4   l = L4[i];
#pragma unroll
        for (int k = 0; k < K; ++k) {
            float m;
            m = (l.x == k) ? 1.f : 0.f; accS[k] = fmaf(m, s.x, accS[k]); accT[k] = fmaf(m, t.x, accT[k]);
            m = (l.y == k) ? 1.f : 0.f; accS[k] = fmaf(m, s.y, accS[k]); accT[k] = fmaf(m, t.y, accT[k]);
            m = (l.z == k) ? 1.f : 0.f; accS[k] = fmaf(m, s.z, accS[k]); accT[k] = fmaf(m, t.z, accT[k]);
            m = (l.w == k) ? 1.f : 0.f; accS[k] = fmaf(m, s.w, accS[k]); accT[k] = fmaf(m, t.w, accT[k]);
        }
    }

    // cross-thread reduce: wave shuffle (6 steps) -> LDS (4 waves) -> global
    __shared__ float redS[4 * K], redT[4 * K];
    const int lane = tid & 63, wv = tid >> 6;
#pragma unroll
    for (int k = 0; k < K; ++k) {
        float vs = accS[k], vt = accT[k];
#pragma unroll
        for (int off = 32; off > 0; off >>= 1) {
            vs += __shfl_down(vs, off);
            vt += __shfl_down(vt, off);
        }
        if (lane == 0) { redS[wv * K + k] = vs; redT[wv * K + k] = vt; }
    }
    __syncthreads();
    if (tid < K) {
        float vs = redS[tid] + redS[K + tid] + redS[2 * K + tid] + redS[3 * K + tid];
        float vt = redT[tid] + redT[K + tid] + redT[2 * K + tid] + redT[3 * K + tid];
        if (NS == SPLIT) {
            pS[(size_t)bid * K + tid] = vs;
            pT[(size_t)bid * K + tid] = vt;
        } else {
            atomicAdd(&pS[(size_t)plane * K + tid], vs);
            atomicAdd(&pT[(size_t)plane * K + tid], vt);
        }
    }

    // label counts: only the 4 blocks with c==0 (block-uniform branch)
    if (c == 0) {
        int cnt[K];
#pragma unroll
        for (int k = 0; k < K; ++k) cnt[k] = 0;
        for (int i = tid; i < CHUNK / 4; i += NT) {
            int4 l = L4[i];
#pragma unroll
            for (int k = 0; k < K; ++k)
                cnt[k] += (l.x == k) + (l.y == k) + (l.z == k) + (l.w == k);
        }
        __shared__ int redc[4 * K];
#pragma unroll
        for (int k = 0; k < K; ++k) {
            int v = cnt[k];
#pragma unroll
            for (int off = 32; off > 0; off >>= 1) v += __shfl_down(v, off);
            if (lane == 0) redc[wv * K + k] = v;
        }
        __syncthreads();
        if (tid < K)
            pC[(b * SPLIT + chunk) * K + tid] =
                redc[tid] + redc[K + tid] + redc[2 * K + tid] + redc[3 * K + tid];
    }
}

// ---------------------------------------------------------------------------
// K2: grid = 2 blocks (one per batch) x 256 threads. Counts precomputed by
// K1's c==0 blocks. Centers sum NS partial slots. Pairwise dots exploit
// symmetry: 190 upper-triangle tasks with fused S/T accumulation.
// ---------------------------------------------------------------------------
template <int NS>
__global__ __launch_bounds__(NT) void finalize_kernel(
    const float* __restrict__ pS, const float* __restrict__ pT,
    const int* __restrict__ pC, float* __restrict__ out)
{
    __shared__ float centS[K * CP];
    __shared__ float centT[K * CP];
    __shared__ float cntf[K];
    __shared__ float dS[K * K], dT[K * K];
    __shared__ float red[NT];
    const int tid = threadIdx.x;
    const int b   = blockIdx.x;

    if (tid < K) {
        int cv = 0;
#pragma unroll
        for (int ch = 0; ch < SPLIT; ++ch) cv += pC[(b * SPLIT + ch) * K + tid];
        cntf[tid] = (float)cv + 1e-6f;
    }
    __syncthreads();

    // centers: [k][c] layout, padded stride; sum NS partial slots
    for (int j = tid; j < NUM_C * K; j += NT) {
        int c = j / K, k = j - (j / K) * K;
        size_t base = ((size_t)(b * NUM_C + c) * NS) * K + k;
        float sS = 0.f, sT = 0.f;
#pragma unroll
        for (int ch = 0; ch < NS; ++ch) {
            sS += pS[base + (size_t)ch * K];
            sT += pT[base + (size_t)ch * K];
        }
        float cn = cntf[k];
        centS[k * CP + c] = sS / cn;
        centT[k * CP + c] = sT / cn;
    }
    __syncthreads();

    // upper-triangle pairwise dots: q in [0, K*(K+1)/2) = [0,190)
    for (int q = tid; q < K * (K + 1) / 2; q += NT) {
        int i = 0, r = q;
        while (r >= K - i) { r -= K - i; ++i; }
        int j = i + r;
        const float4* Si = (const float4*)(centS + i * CP);
        const float4* Sj = (const float4*)(centS + j * CP);
        const float4* Ti = (const float4*)(centT + i * CP);
        const float4* Tj = (const float4*)(centT + j * CP);
        float ds = 0.f, dt = 0.f;
        for (int c4 = 0; c4 < NUM_C / 4; ++c4) {
            float4 xs = Si[c4], ys = Sj[c4];
            ds = fmaf(xs.x, ys.x, ds); ds = fmaf(xs.y, ys.y, ds);
            ds = fmaf(xs.z, ys.z, ds); ds = fmaf(xs.w, ys.w, ds);
            float4 xt = Ti[c4], yt = Tj[c4];
            dt = fmaf(xt.x, yt.x, dt); dt = fmaf(xt.y, yt.y, dt);
            dt = fmaf(xt.z, yt.z, dt); dt = fmaf(xt.w, yt.w, dt);
        }
        dS[i * K + j] = ds; dS[j * K + i] = ds;
        dT[i * K + j] = dt; dT[j * K + i] = dt;
    }
    __syncthreads();

    // cosine-normalize via diagonal + squared diff
    float acc = 0.f;
    for (int p = tid; p < K * K; p += NT) {
        int i = p / K, j = p - (p / K) * K;
        float nsi = fmaxf(sqrtf(dS[i * K + i]), 1e-8f);
        float nsj = fmaxf(sqrtf(dS[j * K + j]), 1e-8f);
        float nti = fmaxf(sqrtf(dT[i * K + i]), 1e-8f);
        float ntj = fmaxf(sqrtf(dT[j * K + j]), 1e-8f);
        float d = dS[p] / (nsi * nsj) - dT[p] / (nti * ntj);
        acc = fmaf(d, d, acc);
    }
    red[tid] = acc;
    __syncthreads();
    for (int s = NT / 2; s > 0; s >>= 1) {
        if (tid < s) red[tid] += red[tid + s];
        __syncthreads();
    }
    if (tid == 0)
        atomicAdd(out, red[0] * (1.0f / (2.0f * K * K)));  // mean over [B,K,K]
}

extern "C" void kernel_launch(void* const* d_in, const int* in_sizes, int n_in,
                              void* d_out, int out_size, void* d_ws, size_t ws_size,
                              hipStream_t stream) {
    const float* S   = (const float*)d_in[0];   // preds_S  [2,512,128,256] fp32
    const float* T   = (const float*)d_in[1];   // preds_T  [2,512,128,256] fp32
    const int*   lbl = (const int*)d_in[2];     // target   [2,1,128,256] int32
    float* out = (float*)d_out;

    const size_t nPlane = (size_t)2 * NUM_C;            // 1024
    const size_t needBig =
        2 * nPlane * SPLIT * K * sizeof(float)          // pS + pT, SPLIT slots (~311 KB)
        + (size_t)2 * SPLIT * K * sizeof(int);          // pC

    if (ws_size >= needBig) {
        // deterministic path: disjoint per-chunk partial slots
        float* pS = (float*)d_ws;
        float* pT = pS + nPlane * SPLIT * K;
        int*   pC = (int*)(pT + nPlane * SPLIT * K);
        seg_sum_kernel<SPLIT><<<2 * NUM_C * SPLIT, NT, 0, stream>>>(S, T, lbl, pS, pT, pC, out);
        finalize_kernel<SPLIT><<<2, NT, 0, stream>>>(pS, pT, pC, out);
    } else {
        // compact fallback: atomic combine into single slot per plane
        float* pS = (float*)d_ws;
        float* pT = pS + nPlane * K;
        int*   pC = (int*)(pT + nPlane * K);
        hipMemsetAsync(pS, 0, 2 * nPlane * K * sizeof(float), stream);
        seg_sum_kernel<1><<<2 * NUM_C * SPLIT, NT, 0, stream>>>(S, T, lbl, pS, pT, pC, out);
        finalize_kernel<1><<<2, NT, 0, stream>>>(pS, pT, pC, out);
    }
}